// Round 7
// baseline (187.717 us; speedup 1.0000x reference)
//
#include <hip/hip_runtime.h>
#include <hip/hip_bf16.h>
#include <stdint.h>

#define BATCH 8
#define CCH   512
#define NHD   8
#define HD    64
#define LLEN  4096
#define M1    1536

typedef __bf16 bf16x8 __attribute__((ext_vector_type(8)));
typedef __bf16 bf16x4 __attribute__((ext_vector_type(4)));
typedef float  f32x4  __attribute__((ext_vector_type(4)));

__device__ __forceinline__ f32x4 mfma16(bf16x8 a, bf16x8 b, f32x4 c) {
  return __builtin_amdgcn_mfma_f32_16x16x32_bf16(a, b, c, 0, 0, 0);
}

// async global->LDS, 16B per lane. LDS dest is wave-uniform base + lane*16.
__device__ __forceinline__ void gload_lds16(const void* g, void* l) {
  __builtin_amdgcn_global_load_lds(
      (const __attribute__((address_space(1))) uint32_t*)(uintptr_t)g,
      (__attribute__((address_space(3))) uint32_t*)(uintptr_t)l,
      16, 0, 0);
}

// ---------------- pack weights/biases to bf16 ----------------
__global__ void pack_w(const float* __restrict__ wq, const float* __restrict__ wk,
                       const float* __restrict__ wv,
                       const float* __restrict__ bq, const float* __restrict__ bk,
                       const float* __restrict__ bv,
                       __bf16* __restrict__ wqkvb, float* __restrict__ biasq) {
  const int n = M1 * CCH + M1;
  for (int i = blockIdx.x * blockDim.x + threadIdx.x; i < n; i += gridDim.x * blockDim.x) {
    if (i < M1 * CCH) {
      int r = i >> 9, c = i & 511;
      float v = (r < 512) ? wq[r * 512 + c]
              : (r < 1024) ? wk[(r - 512) * 512 + c]
                           : wv[(r - 1024) * 512 + c];
      wqkvb[i] = (__bf16)v;
    } else {
      int j = i - M1 * CCH;
      biasq[j] = (j < 512) ? bq[j] : (j < 1024) ? bk[j - 512] : bv[j - 1024];
    }
  }
}

// ---------------- x [b][C][L] fp32 -> xt [b][L][C] bf16 (64x64 tiles) ----------------
__global__ __launch_bounds__(256) void transpose_x(const float* __restrict__ x,
                                                   __bf16* __restrict__ xt) {
  __shared__ float tile[64][65];
  const int b = blockIdx.z, c0 = blockIdx.y * 64, l0 = blockIdx.x * 64;
  const int t = threadIdx.x;
  const int lq = (t & 15) * 4, cr = t >> 4;
  const float* xp = x + ((size_t)b * CCH + c0) * LLEN + l0;
#pragma unroll
  for (int q = 0; q < 4; ++q) {
    const int c = cr + q * 16;
    float4 v = *(const float4*)(xp + (size_t)c * LLEN + lq);
    tile[c][lq + 0] = v.x;
    tile[c][lq + 1] = v.y;
    tile[c][lq + 2] = v.z;
    tile[c][lq + 3] = v.w;
  }
  __syncthreads();
  __bf16* xo = xt + ((size_t)b * LLEN + l0) * CCH + c0;
  const int c4 = (t & 15) * 4, lr = t >> 4;
#pragma unroll
  for (int p = 0; p < 4; ++p) {
    const int l = lr + p * 16;
    bf16x4 o;
#pragma unroll
    for (int i = 0; i < 4; ++i) o[i] = (__bf16)tile[c4 + i][l];
    *(bf16x4*)(xo + (size_t)l * CCH + c4) = o;
  }
}

// ======== 256x256 GEMM: BK=32, 16 K-tiles, 2 phases/tile, 4x32KB LDS buffers ========
// Deep prefetch: stage tile t+3 during tile t (issue-to-wait ~6 phases, covers HBM lat).
// vmcnt(8) once per tile, never 0 until drain. Swizzle: slot = chunk ^ ((row>>1)&3)
// -> 16-lane frag reads hit all 8 bank-groups x2 (2-way = free).
// Buffer (t&3)*16384 el: A unit [0,8192) = 256 rows x 32 el, B unit [8192,16384).
#define STAGE_A(tt)                                                           \
  {                                                                           \
    const int dbase = ((tt) & 3) * 16384;                                     \
    const int tK = (tt) * 32;                                                 \
    gload_lds16(Ag + srcOff + tK,         lds + dbase + tid * 8);             \
    gload_lds16(Ag + srcOff + tK + 65536, lds + dbase + 4096 + tid * 8);      \
  }
#define STAGE_B(tt)                                                           \
  {                                                                           \
    const int dbase = ((tt) & 3) * 16384 + 8192;                              \
    const int tK = (tt) * 32;                                                 \
    gload_lds16(Bg + srcOff + tK,         lds + dbase + tid * 8);             \
    gload_lds16(Bg + srcOff + tK + 65536, lds + dbase + 4096 + tid * 8);      \
  }

template <int EPI>
__global__ __launch_bounds__(512, 1) void gemm256(
    const __bf16* __restrict__ A, const __bf16* __restrict__ Bm,
    const float* __restrict__ bias,
    __bf16* __restrict__ qt, __bf16* __restrict__ kcm, __bf16* __restrict__ vcm,
    float* __restrict__ out) {
  __shared__ __attribute__((aligned(16))) __bf16 lds[4 * 16384];  // 128KB
  const int b  = blockIdx.z;
  const int n0 = blockIdx.x * 256;
  const int m0 = blockIdx.y * 256;
  const int tid = threadIdx.x;
  const int ll = tid & 63, w = tid >> 6;  // 8 waves
  const int wr = w >> 2, wc = w & 3;      // 2M x 4N, wave-tile 128x64
  const int lhi = ll >> 4, llo = ll & 15;

  // fragment read offsets: row's chunk lhi stored at slot lhi ^ ((row>>1)&3)
  const int slotE = ((lhi ^ ((llo >> 1) & 3)) << 3);
  int aOff[8], bOff[4];
#pragma unroll
  for (int m = 0; m < 8; ++m) aOff[m] = (wr * 128 + m * 16 + llo) * 32 + slotE;
#pragma unroll
  for (int n = 0; n < 4; ++n) bOff[n] = 8192 + (wc * 64 + n * 16 + llo) * 32 + slotE;

  // staging decode (inverse swizzle): dest slot tid -> row tid>>2,
  // stored chunk (tid&3) ^ ((row>>1)&3)
  const int sRow = tid >> 2;
  const int srcOff = sRow * CCH + ((((tid & 3) ^ ((sRow >> 1) & 3))) << 3);

  const __bf16* Ag = (EPI == 0 ? A + (size_t)m0 * CCH
                               : A + (size_t)b * CCH * CCH + (size_t)m0 * CCH);
  const __bf16* Bg = Bm + ((size_t)b * LLEN + n0) * CCH;

  f32x4 acc[8][4] = {};

  // prologue: stage tiles 0,1,2; tile0 resident, 8 loads (tiles 1,2) in flight
  STAGE_A(0) STAGE_B(0) STAGE_A(1) STAGE_B(1) STAGE_A(2) STAGE_B(2)
  asm volatile("s_waitcnt vmcnt(8)" ::: "memory");
  __builtin_amdgcn_s_barrier();

  for (int t = 0; t < 16; ++t) {
    const int cb = (t & 3) * 16384;
    bf16x8 aq[8], bq[4];
    // ---- phase 0: all A frags + B frags 0,1 ----
#pragma unroll
    for (int m = 0; m < 8; ++m) aq[m] = *(const bf16x8*)(lds + cb + aOff[m]);
    bq[0] = *(const bf16x8*)(lds + cb + bOff[0]);
    bq[1] = *(const bf16x8*)(lds + cb + bOff[1]);
    if (t <= 12) STAGE_A(t + 3)
    __builtin_amdgcn_s_barrier();
    asm volatile("s_waitcnt lgkmcnt(0)" ::: "memory");
    __builtin_amdgcn_sched_barrier(0);
    __builtin_amdgcn_s_setprio(1);
#pragma unroll
    for (int m = 0; m < 8; ++m) {
      acc[m][0] = mfma16(aq[m], bq[0], acc[m][0]);
      acc[m][1] = mfma16(aq[m], bq[1], acc[m][1]);
    }
    __builtin_amdgcn_s_setprio(0);
    __builtin_amdgcn_s_barrier();
    // ---- phase 1: B frags 2,3 (A reused) ----
    bq[2] = *(const bf16x8*)(lds + cb + bOff[2]);
    bq[3] = *(const bf16x8*)(lds + cb + bOff[3]);
    if (t <= 12) STAGE_B(t + 3)
    if (t <= 12)      asm volatile("s_waitcnt vmcnt(8)" ::: "memory");
    else if (t == 13) asm volatile("s_waitcnt vmcnt(4)" ::: "memory");
    else if (t == 14) asm volatile("s_waitcnt vmcnt(0)" ::: "memory");
    __builtin_amdgcn_s_barrier();
    asm volatile("s_waitcnt lgkmcnt(0)" ::: "memory");
    __builtin_amdgcn_sched_barrier(0);
    __builtin_amdgcn_s_setprio(1);
#pragma unroll
    for (int m = 0; m < 8; ++m) {
      acc[m][2] = mfma16(aq[m], bq[2], acc[m][2]);
      acc[m][3] = mfma16(aq[m], bq[3], acc[m][3]);
    }
    __builtin_amdgcn_s_setprio(0);
    __builtin_amdgcn_s_barrier();
  }

  // epilogue
#pragma unroll
  for (int i = 0; i < 8; ++i) {
    const int o0 = m0 + wr * 128 + i * 16 + lhi * 4;
#pragma unroll
    for (int j = 0; j < 4; ++j) {
      const int col = n0 + wc * 64 + j * 16 + llo;
      if (EPI == 0) {
        if (m0 < 512) {
          bf16x4 pk;
#pragma unroll
          for (int r = 0; r < 4; ++r) {
            float tv = acc[i][j][r] + bias[o0 + r];
            tv = tv > 0.f ? tv + 1.f : __expf(tv);
            pk[r] = (__bf16)tv;
          }
          *(bf16x4*)(qt + ((size_t)b * LLEN + col) * CCH + o0) = pk;
        } else if (m0 < 1024) {
#pragma unroll
          for (int r = 0; r < 4; ++r) {
            float tv = acc[i][j][r] + bias[o0 + r];
            tv = tv > 0.f ? tv + 1.f : __expf(tv);
            kcm[((size_t)b * CCH + (o0 - 512 + r)) * LLEN + col] = (__bf16)tv;
          }
        } else {
#pragma unroll
          for (int r = 0; r < 4; ++r)
            vcm[((size_t)b * CCH + (o0 - 1024 + r)) * LLEN + col] =
                (__bf16)(acc[i][j][r] + bias[o0 + r]);
        }
      } else {
#pragma unroll
        for (int r = 0; r < 4; ++r)
          out[((size_t)b * CCH + o0 + r) * LLEN + col] = acc[i][j][r] + bias[o0 + r];
      }
    }
  }
}

// ---------------- KV partials + fused Ksum partials (4 waves, LDS reduce) ----------------
__global__ __launch_bounds__(256) void kv_part_k(const __bf16* __restrict__ kcm,
                                                 const __bf16* __restrict__ vcm,
                                                 float* __restrict__ part,
                                                 float* __restrict__ part_ks) {
  __shared__ float red[8192];
  __shared__ float ksred[4][64];
  const int lc = blockIdx.x, bh = blockIdx.y;
  const int b = bh >> 3, h = bh & 7;
  const int tid = threadIdx.x;
  const int w = tid >> 6, ll = tid & 63, lhi = ll >> 4, llo = ll & 15;
  const __bf16* Kp = kcm + ((size_t)b * CCH + h * 64) * LLEN;
  const __bf16* Vp = vcm + ((size_t)b * CCH + h * 64) * LLEN;
  f32x4 acc[4][4];
#pragma unroll
  for (int i = 0; i < 4; ++i)
#pragma unroll
    for (int j = 0; j < 4; ++j) acc[i][j] = (f32x4){0.f, 0.f, 0.f, 0.f};
  float ks[4] = {0.f, 0.f, 0.f, 0.f};
  const int base = lc * 512 + w * 128 + lhi * 8;
#pragma unroll
  for (int kt = 0; kt < 4; ++kt) {
    const int k0 = base + kt * 32;
    bf16x8 af[4], bfr[4];
#pragma unroll
    for (int i = 0; i < 4; ++i) af[i]  = *(const bf16x8*)(Kp + (size_t)(i * 16 + llo) * LLEN + k0);
#pragma unroll
    for (int i = 0; i < 4; ++i) bfr[i] = *(const bf16x8*)(Vp + (size_t)(i * 16 + llo) * LLEN + k0);
#pragma unroll
    for (int i = 0; i < 4; ++i)
#pragma unroll
      for (int r = 0; r < 8; ++r) ks[i] += (float)af[i][r];
#pragma unroll
    for (int i = 0; i < 4; ++i)
#pragma unroll
      for (int j = 0; j < 4; ++j) acc[i][j] = mfma16(af[i], bfr[j], acc[i][j]);
  }
#pragma unroll
  for (int i = 0; i < 4; ++i) {
    float s = ks[i];
    s += __shfl_xor(s, 16);
    s += __shfl_xor(s, 32);
    if (lhi == 0) ksred[w][i * 16 + llo] = s;
  }
  if (w >= 2) {
#pragma unroll
    for (int i = 0; i < 4; ++i)
#pragma unroll
      for (int j = 0; j < 4; ++j)
        *(f32x4*)(red + (((w - 2) * 16 + i * 4 + j) << 8) + ll * 4) = acc[i][j];
  }
  __syncthreads();
  if (w < 2) {
#pragma unroll
    for (int i = 0; i < 4; ++i)
#pragma unroll
      for (int j = 0; j < 4; ++j)
        acc[i][j] += *(const f32x4*)(red + ((w * 16 + i * 4 + j) << 8) + ll * 4);
  }
  float ksv = 0.f;
  if (w == 1) ksv = ksred[0][ll] + ksred[1][ll] + ksred[2][ll] + ksred[3][ll];
  __syncthreads();
  if (w == 1) {
#pragma unroll
    for (int i = 0; i < 4; ++i)
#pragma unroll
      for (int j = 0; j < 4; ++j)
        *(f32x4*)(red + ((i * 4 + j) << 8) + ll * 4) = acc[i][j];
    part_ks[((size_t)lc * 64 + bh) * 64 + ll] = ksv;
  }
  __syncthreads();
  if (w == 0) {
    float* op = part + ((size_t)lc * 64 + bh) * 4096;
#pragma unroll
    for (int i = 0; i < 4; ++i)
#pragma unroll
      for (int j = 0; j < 4; ++j) {
        acc[i][j] += *(const f32x4*)(red + ((i * 4 + j) << 8) + ll * 4);
#pragma unroll
        for (int r = 0; r < 4; ++r) {
          int d = i * 16 + lhi * 4 + r, v = j * 16 + llo;
          op[d * 64 + v] = acc[i][j][r];
        }
      }
  }
}

__global__ void kv_red_k(const float* __restrict__ part, float* __restrict__ kv) {
  const int i = blockIdx.x * blockDim.x + threadIdx.x;
  float s = 0.f;
#pragma unroll
  for (int lc = 0; lc < 8; ++lc) s += part[(size_t)lc * 262144 + i];
  kv[i] = s;
}

__global__ void ksum_red_k(const float* __restrict__ part_ks, float* __restrict__ ksum) {
  const int i = blockIdx.x * blockDim.x + threadIdx.x;
  float s = 0.f;
#pragma unroll
  for (int lc = 0; lc < 8; ++lc) s += part_ks[(size_t)lc * 4096 + i];
  ksum[i] = s;
}

// ---------------- fold: wokv[b][o][h*64+d] = sum_v wo[o][h*64+v] * kv[b][h][d][v] ----------------
__global__ __launch_bounds__(256) void fold_k(const float* __restrict__ wo,
                                              const float* __restrict__ kvb,
                                              __bf16* __restrict__ wokv) {
  const int h = blockIdx.x, b = blockIdx.y;
  const int tid = threadIdx.x;
  const int w = tid >> 6, ll = tid & 63, lhi = ll >> 4, llo = ll & 15;
  const float* kvp = kvb + (size_t)(b * 8 + h) * 4096;
  f32x4 acc[8][4] = {};
#pragma unroll
  for (int ks = 0; ks < 2; ++ks) {
    bf16x8 bfr[4];
#pragma unroll
    for (int n = 0; n < 4; ++n) {
      const float* p = kvp + (n * 16 + llo) * 64 + ks * 32 + lhi * 8;
      bf16x8 v;
#pragma unroll
      for (int e = 0; e < 8; ++e) v[e] = (__bf16)p[e];
      bfr[n] = v;
    }
#pragma unroll
    for (int m = 0; m < 8; ++m) {
      const float* p = wo + (size_t)(w * 128 + m * 16 + llo) * 512 + h * 64 + ks * 32 + lhi * 8;
      bf16x8 av;
#pragma unroll
      for (int e = 0; e < 8; ++e) av[e] = (__bf16)p[e];
#pragma unroll
      for (int n = 0; n < 4; ++n) acc[m][n] = mfma16(av, bfr[n], acc[m][n]);
    }
  }
#pragma unroll
  for (int m = 0; m < 8; ++m)
#pragma unroll
    for (int n = 0; n < 4; ++n)
#pragma unroll
      for (int r = 0; r < 4; ++r) {
        int o = w * 128 + m * 16 + lhi * 4 + r;
        int d = n * 16 + llo;
        wokv[((size_t)b * 512 + o) * 512 + h * 64 + d] = (__bf16)acc[m][n][r];
      }
}

// ---------------- zscale: qt[b][l][h*64+d] *= 1/(Q_h[l]·Ksum_h + eps), in place ------
__global__ __launch_bounds__(256) void zscale_k(__bf16* __restrict__ qt,
                                                const float* __restrict__ ksumf) {
  __shared__ float ks[512];
  const int b = blockIdx.y;
  const int l0 = blockIdx.x * 32;
  const int tid = threadIdx.x;
  ks[tid]       = ksumf[b * 512 + tid];
  ks[tid + 256] = ksumf[b * 512 + tid + 256];
  __syncthreads();
  const int r = tid >> 3, h = tid & 7;  // 32 rows/block, 8 heads
  __bf16* qp = qt + ((size_t)b * LLEN + l0 + r) * CCH + h * 64;
  bf16x8 v[8];
  float dot = 0.f;
#pragma unroll
  for (int e = 0; e < 8; ++e) {
    v[e] = *(const bf16x8*)(qp + e * 8);
#pragma unroll
    for (int i = 0; i < 8; ++i) dot += (float)v[e][i] * ks[h * 64 + e * 8 + i];
  }
  const float z = 1.0f / (dot + 1e-6f);
#pragma unroll
  for (int e = 0; e < 8; ++e) {
    bf16x8 o;
#pragma unroll
    for (int i = 0; i < 8; ++i) o[i] = (__bf16)((float)v[e][i] * z);
    *(bf16x8*)(qp + e * 8) = o;
  }
}

extern "C" void kernel_launch(void* const* d_in, const int* in_sizes, int n_in,
                              void* d_out, int out_size, void* d_ws, size_t ws_size,
                              hipStream_t stream) {
  const float* x  = (const float*)d_in[0];
  const float* wq = (const float*)d_in[1];
  const float* bq = (const float*)d_in[2];
  const float* wk = (const float*)d_in[3];
  const float* bk = (const float*)d_in[4];
  const float* wv = (const float*)d_in[5];
  const float* bv = (const float*)d_in[6];
  const float* wo = (const float*)d_in[7];
  const float* bo = (const float*)d_in[8];
  float* out = (float*)d_out;

  char* p = (char*)d_ws;
  __bf16* xt    = (__bf16*)p; p += (size_t)BATCH * LLEN * CCH * 2;  // 32MB
  __bf16* qt    = (__bf16*)p; p += (size_t)BATCH * LLEN * CCH * 2;  // 32MB
  __bf16* kcm   = (__bf16*)p; p += (size_t)BATCH * CCH * LLEN * 2;  // 32MB
  __bf16* vcm   = (__bf16*)p; p += (size_t)BATCH * CCH * LLEN * 2;  // 32MB
  __bf16* wqkvb = (__bf16*)p; p += (size_t)M1 * CCH * 2;
  float*  biasq = (float*)p;  p += (size_t)M1 * 4;
  float*  ksumf = (float*)p;  p += (size_t)BATCH * CCH * 4;
  float*  part  = (float*)p;  p += (size_t)8 * 64 * HD * HD * 4;    // 8MB
  float*  kvb   = (float*)p;  p += (size_t)64 * HD * HD * 4;        // 1MB
  float*  pks   = (float*)p;  p += (size_t)8 * 64 * 64 * 4;         // 128KB
  __bf16* wokv  = (__bf16*)p; p += (size_t)BATCH * CCH * CCH * 2;   // 4MB

  pack_w<<<1024, 256, 0, stream>>>(wq, wk, wv, bq, bk, bv, wqkvb, biasq);
  transpose_x<<<dim3(64, 8, BATCH), 256, 0, stream>>>(x, xt);
  gemm256<0><<<dim3(16, 6, BATCH), 512, 0, stream>>>(wqkvb, xt, biasq, qt, kcm, vcm, nullptr);
  kv_part_k<<<dim3(8, 64), 256, 0, stream>>>(kcm, vcm, part, pks);
  kv_red_k<<<1024, 256, 0, stream>>>(part, kvb);
  ksum_red_k<<<16, 256, 0, stream>>>(pks, ksumf);
  fold_k<<<dim3(8, 8), 256, 0, stream>>>(wo, kvb, wokv);
  zscale_k<<<dim3(128, BATCH), 256, 0, stream>>>(qt, ksumf);
  gemm256<1><<<dim3(16, 2, BATCH), 512, 0, stream>>>(wokv, qt, bo, nullptr, nullptr, vcm, out);
}

// Round 8
// 182.717 us; speedup vs baseline: 1.0274x; 1.0274x over previous
//
#include <hip/hip_runtime.h>
#include <hip/hip_bf16.h>
#include <stdint.h>

#define BATCH 8
#define CCH   512
#define NHD   8
#define HD    64
#define LLEN  4096
#define M1    1536

typedef __bf16 bf16x8 __attribute__((ext_vector_type(8)));
typedef __bf16 bf16x4 __attribute__((ext_vector_type(4)));
typedef float  f32x4  __attribute__((ext_vector_type(4)));

__device__ __forceinline__ f32x4 mfma16(bf16x8 a, bf16x8 b, f32x4 c) {
  return __builtin_amdgcn_mfma_f32_16x16x32_bf16(a, b, c, 0, 0, 0);
}

__device__ __forceinline__ void gload_lds16(const void* g, void* l) {
  __builtin_amdgcn_global_load_lds(
      (const __attribute__((address_space(1))) uint32_t*)(uintptr_t)g,
      (__attribute__((address_space(3))) uint32_t*)(uintptr_t)l,
      16, 0, 0);
}

// ---------------- pack weights/biases to bf16 ----------------
__global__ void pack_w(const float* __restrict__ wq, const float* __restrict__ wk,
                       const float* __restrict__ wv,
                       const float* __restrict__ bq, const float* __restrict__ bk,
                       const float* __restrict__ bv,
                       __bf16* __restrict__ wqkvb, float* __restrict__ biasq) {
  const int n = M1 * CCH + M1;
  for (int i = blockIdx.x * blockDim.x + threadIdx.x; i < n; i += gridDim.x * blockDim.x) {
    if (i < M1 * CCH) {
      int r = i >> 9, c = i & 511;
      float v = (r < 512) ? wq[r * 512 + c]
              : (r < 1024) ? wk[(r - 512) * 512 + c]
                           : wv[(r - 1024) * 512 + c];
      wqkvb[i] = (__bf16)v;
    } else {
      int j = i - M1 * CCH;
      biasq[j] = (j < 512) ? bq[j] : (j < 1024) ? bk[j - 512] : bv[j - 1024];
    }
  }
}

// ---------------- x [b][C][L] fp32 -> xt [b][L][C] bf16 (64x64 tiles) ----------------
__global__ __launch_bounds__(256) void transpose_x(const float* __restrict__ x,
                                                   __bf16* __restrict__ xt) {
  __shared__ float tile[64][65];
  const int b = blockIdx.z, c0 = blockIdx.y * 64, l0 = blockIdx.x * 64;
  const int t = threadIdx.x;
  const int lq = (t & 15) * 4, cr = t >> 4;
  const float* xp = x + ((size_t)b * CCH + c0) * LLEN + l0;
#pragma unroll
  for (int q = 0; q < 4; ++q) {
    const int c = cr + q * 16;
    float4 v = *(const float4*)(xp + (size_t)c * LLEN + lq);
    tile[c][lq + 0] = v.x;
    tile[c][lq + 1] = v.y;
    tile[c][lq + 2] = v.z;
    tile[c][lq + 3] = v.w;
  }
  __syncthreads();
  __bf16* xo = xt + ((size_t)b * LLEN + l0) * CCH + c0;
  const int c8 = (t & 7) * 8, lr = t >> 3;  // 32 rows/pass, 16B writes
#pragma unroll
  for (int p = 0; p < 2; ++p) {
    const int l = lr + p * 32;
    bf16x8 o;
#pragma unroll
    for (int i = 0; i < 8; ++i) o[i] = (__bf16)tile[c8 + i][l];
    *(bf16x8*)(xo + (size_t)l * CCH + c8) = o;
  }
}

// ======== 128x128 GEMM, BK=32, double-buffered 32KB LDS, 4 waves, 4 blocks/CU ========
// Swizzle (0-conflict, r6-verified): row's 16B chunk c stored at slot c ^ ((row>>1)&3).
// Simple m97/m99 loop: stage(t+1) -> frag reads(t) -> MFMA -> __syncthreads().
// Inter-block overlap (4 blocks/CU) hides stage latency + barrier drains (m114).
#define STG128(tt, buf)                                                      \
  {                                                                          \
    const __bf16* As_ = Ag + (tt) * 32;                                      \
    const __bf16* Bs_ = Bg + (tt) * 32;                                      \
    __bf16* dA = lds + (buf) * 8192;                                         \
    __bf16* dB = dA + 4096;                                                  \
    gload_lds16(As_ + srcOff1, dA + tid * 8);                                \
    gload_lds16(As_ + srcOff2, dA + tid * 8 + 2048);                         \
    gload_lds16(Bs_ + srcOff1, dB + tid * 8);                                \
    gload_lds16(Bs_ + srcOff2, dB + tid * 8 + 2048);                         \
  }

template <int EPI>
__global__ __launch_bounds__(256, 4) void gemm128(
    const __bf16* __restrict__ A, const __bf16* __restrict__ Bm,
    const float* __restrict__ bias,
    __bf16* __restrict__ qt, __bf16* __restrict__ kcm, __bf16* __restrict__ vcm,
    float* __restrict__ out) {
  __shared__ __attribute__((aligned(16))) __bf16 lds[2 * 8192];  // 32KB
  const int b  = blockIdx.z;
  const int n0 = blockIdx.x * 128;
  const int m0 = blockIdx.y * 128;
  const int tid = threadIdx.x;
  const int ll = tid & 63, w = tid >> 6;  // 4 waves, 2M x 2N
  const int wr = w >> 1, wc = w & 1;
  const int lhi = ll >> 4, llo = ll & 15;

  // frag read offsets: (row>>1)&3 == (llo>>1)&3 for 16-aligned frag bases
  const int slotE = ((lhi ^ ((llo >> 1) & 3)) << 3);
  int aOff[4], bOff[4];
#pragma unroll
  for (int m = 0; m < 4; ++m) aOff[m] = (wr * 64 + m * 16 + llo) * 32 + slotE;
#pragma unroll
  for (int n = 0; n < 4; ++n) bOff[n] = 4096 + (wc * 64 + n * 16 + llo) * 32 + slotE;

  // staging (inverse swizzle): slot s -> row s>>2, stored chunk (s&3)^((row>>1)&3)
  const int s1 = tid, s2 = tid + 256;
  const int r1 = s1 >> 2, r2s = s2 >> 2;
  const int srcOff1 = r1 * CCH + (((s1 & 3) ^ ((r1 >> 1) & 3)) << 3);
  const int srcOff2 = r2s * CCH + (((s2 & 3) ^ ((r2s >> 1) & 3)) << 3);

  const __bf16* Ag = (EPI == 0 ? A + (size_t)m0 * CCH
                               : A + (size_t)b * CCH * CCH + (size_t)m0 * CCH);
  const __bf16* Bg = Bm + ((size_t)b * LLEN + n0) * CCH;

  f32x4 acc[4][4] = {};

  STG128(0, 0)
  __syncthreads();  // tile0 resident (barrier drains vmcnt)

  for (int t = 0; t < 16; ++t) {
    const int buf = t & 1;
    if (t < 15) STG128(t + 1, buf ^ 1)
    bf16x8 af[4], bfr[4];
    const __bf16* base = lds + buf * 8192;
#pragma unroll
    for (int m = 0; m < 4; ++m) af[m] = *(const bf16x8*)(base + aOff[m]);
#pragma unroll
    for (int n = 0; n < 4; ++n) bfr[n] = *(const bf16x8*)(base + bOff[n]);
#pragma unroll
    for (int m = 0; m < 4; ++m)
#pragma unroll
      for (int n = 0; n < 4; ++n) acc[m][n] = mfma16(af[m], bfr[n], acc[m][n]);
    __syncthreads();  // drains vmcnt -> next buffer resident
  }

  // epilogue
#pragma unroll
  for (int i = 0; i < 4; ++i) {
    const int o0 = m0 + wr * 64 + i * 16 + lhi * 4;
#pragma unroll
    for (int j = 0; j < 4; ++j) {
      const int col = n0 + wc * 64 + j * 16 + llo;
      if (EPI == 0) {
        if (m0 < 512) {
          bf16x4 pk;
#pragma unroll
          for (int r = 0; r < 4; ++r) {
            float tv = acc[i][j][r] + bias[o0 + r];
            tv = tv > 0.f ? tv + 1.f : __expf(tv);
            pk[r] = (__bf16)tv;
          }
          *(bf16x4*)(qt + ((size_t)b * LLEN + col) * CCH + o0) = pk;
        } else if (m0 < 1024) {
#pragma unroll
          for (int r = 0; r < 4; ++r) {
            float tv = acc[i][j][r] + bias[o0 + r];
            tv = tv > 0.f ? tv + 1.f : __expf(tv);
            kcm[((size_t)b * CCH + (o0 - 512 + r)) * LLEN + col] = (__bf16)tv;
          }
        } else {
#pragma unroll
          for (int r = 0; r < 4; ++r)
            vcm[((size_t)b * CCH + (o0 - 1024 + r)) * LLEN + col] =
                (__bf16)(acc[i][j][r] + bias[o0 + r]);
        }
      } else {
#pragma unroll
        for (int r = 0; r < 4; ++r)
          out[((size_t)b * CCH + o0 + r) * LLEN + col] = acc[i][j][r] + bias[o0 + r];
      }
    }
  }
}

// ---------------- KV partials + fused Ksum partials (4 waves, LDS reduce) ----------------
__global__ __launch_bounds__(256) void kv_part_k(const __bf16* __restrict__ kcm,
                                                 const __bf16* __restrict__ vcm,
                                                 float* __restrict__ part,
                                                 float* __restrict__ part_ks) {
  __shared__ float red[8192];
  __shared__ float ksred[4][64];
  const int lc = blockIdx.x, bh = blockIdx.y;
  const int b = bh >> 3, h = bh & 7;
  const int tid = threadIdx.x;
  const int w = tid >> 6, ll = tid & 63, lhi = ll >> 4, llo = ll & 15;
  const __bf16* Kp = kcm + ((size_t)b * CCH + h * 64) * LLEN;
  const __bf16* Vp = vcm + ((size_t)b * CCH + h * 64) * LLEN;
  f32x4 acc[4][4];
#pragma unroll
  for (int i = 0; i < 4; ++i)
#pragma unroll
    for (int j = 0; j < 4; ++j) acc[i][j] = (f32x4){0.f, 0.f, 0.f, 0.f};
  float ks[4] = {0.f, 0.f, 0.f, 0.f};
  const int base = lc * 512 + w * 128 + lhi * 8;
#pragma unroll
  for (int kt = 0; kt < 4; ++kt) {
    const int k0 = base + kt * 32;
    bf16x8 af[4], bfr[4];
#pragma unroll
    for (int i = 0; i < 4; ++i) af[i]  = *(const bf16x8*)(Kp + (size_t)(i * 16 + llo) * LLEN + k0);
#pragma unroll
    for (int i = 0; i < 4; ++i) bfr[i] = *(const bf16x8*)(Vp + (size_t)(i * 16 + llo) * LLEN + k0);
#pragma unroll
    for (int i = 0; i < 4; ++i)
#pragma unroll
      for (int r = 0; r < 8; ++r) ks[i] += (float)af[i][r];
#pragma unroll
    for (int i = 0; i < 4; ++i)
#pragma unroll
      for (int j = 0; j < 4; ++j) acc[i][j] = mfma16(af[i], bfr[j], acc[i][j]);
  }
#pragma unroll
  for (int i = 0; i < 4; ++i) {
    float s = ks[i];
    s += __shfl_xor(s, 16);
    s += __shfl_xor(s, 32);
    if (lhi == 0) ksred[w][i * 16 + llo] = s;
  }
  if (w >= 2) {
#pragma unroll
    for (int i = 0; i < 4; ++i)
#pragma unroll
      for (int j = 0; j < 4; ++j)
        *(f32x4*)(red + (((w - 2) * 16 + i * 4 + j) << 8) + ll * 4) = acc[i][j];
  }
  __syncthreads();
  if (w < 2) {
#pragma unroll
    for (int i = 0; i < 4; ++i)
#pragma unroll
      for (int j = 0; j < 4; ++j)
        acc[i][j] += *(const f32x4*)(red + ((w * 16 + i * 4 + j) << 8) + ll * 4);
  }
  float ksv = 0.f;
  if (w == 1) ksv = ksred[0][ll] + ksred[1][ll] + ksred[2][ll] + ksred[3][ll];
  __syncthreads();
  if (w == 1) {
#pragma unroll
    for (int i = 0; i < 4; ++i)
#pragma unroll
      for (int j = 0; j < 4; ++j)
        *(f32x4*)(red + ((i * 4 + j) << 8) + ll * 4) = acc[i][j];
    part_ks[((size_t)lc * 64 + bh) * 64 + ll] = ksv;
  }
  __syncthreads();
  if (w == 0) {
    float* op = part + ((size_t)lc * 64 + bh) * 4096;
#pragma unroll
    for (int i = 0; i < 4; ++i)
#pragma unroll
      for (int j = 0; j < 4; ++j) {
        acc[i][j] += *(const f32x4*)(red + ((i * 4 + j) << 8) + ll * 4);
#pragma unroll
        for (int r = 0; r < 4; ++r) {
          int d = i * 16 + lhi * 4 + r, v = j * 16 + llo;
          op[d * 64 + v] = acc[i][j][r];
        }
      }
  }
}

// ---- merged: reduce KV partials + Ksum partials, then fold wokv = wo_h x KV_h ----
__global__ __launch_bounds__(256) void kvfold_k(const float* __restrict__ part,
                                                const float* __restrict__ pks,
                                                const float* __restrict__ wo,
                                                __bf16* __restrict__ wokv,
                                                float* __restrict__ ksumf) {
  __shared__ float kvred[64 * 68];  // [d][v] padded (+4) -> conflict-free col reads
  const int h = blockIdx.x, b = blockIdx.y;
  const int bh = b * 8 + h;
  const int tid = threadIdx.x;
  for (int i = tid; i < 4096; i += 256) {
    float s = 0.f;
#pragma unroll
    for (int lc = 0; lc < 8; ++lc) s += part[(size_t)lc * 262144 + (size_t)bh * 4096 + i];
    kvred[(i >> 6) * 68 + (i & 63)] = s;
  }
  if (tid < 64) {
    float s = 0.f;
#pragma unroll
    for (int lc = 0; lc < 8; ++lc) s += pks[(size_t)lc * 4096 + bh * 64 + tid];
    ksumf[b * 512 + h * 64 + tid] = s;
  }
  __syncthreads();

  const int w = tid >> 6, ll = tid & 63, lhi = ll >> 4, llo = ll & 15;
  f32x4 acc[8][4] = {};
#pragma unroll
  for (int ks = 0; ks < 2; ++ks) {
    bf16x8 bfr[4];
#pragma unroll
    for (int n = 0; n < 4; ++n) {
      const float* p = kvred + (n * 16 + llo) * 68 + ks * 32 + lhi * 8;
      bf16x8 v;
#pragma unroll
      for (int e = 0; e < 8; ++e) v[e] = (__bf16)p[e];
      bfr[n] = v;
    }
#pragma unroll
    for (int m = 0; m < 8; ++m) {
      const float* p = wo + (size_t)(w * 128 + m * 16 + llo) * 512 + h * 64 + ks * 32 + lhi * 8;
      bf16x8 av;
#pragma unroll
      for (int e = 0; e < 8; ++e) av[e] = (__bf16)p[e];
#pragma unroll
      for (int n = 0; n < 4; ++n) acc[m][n] = mfma16(av, bfr[n], acc[m][n]);
    }
  }
#pragma unroll
  for (int m = 0; m < 8; ++m)
#pragma unroll
    for (int n = 0; n < 4; ++n)
#pragma unroll
      for (int r = 0; r < 4; ++r) {
        int o = w * 128 + m * 16 + lhi * 4 + r;
        int d = n * 16 + llo;
        wokv[((size_t)b * 512 + o) * 512 + h * 64 + d] = (__bf16)acc[m][n][r];
      }
}

// ---------------- zscale: qt[b][l][h*64+d] *= 1/(Q_h[l]·Ksum_h + eps), in place ------
__global__ __launch_bounds__(256) void zscale_k(__bf16* __restrict__ qt,
                                                const float* __restrict__ ksumf) {
  __shared__ float ks[512];
  const int b = blockIdx.y;
  const int l0 = blockIdx.x * 32;
  const int tid = threadIdx.x;
  ks[tid]       = ksumf[b * 512 + tid];
  ks[tid + 256] = ksumf[b * 512 + tid + 256];
  __syncthreads();
  const int r = tid >> 3, h = tid & 7;
  __bf16* qp = qt + ((size_t)b * LLEN + l0 + r) * CCH + h * 64;
  bf16x8 v[8];
  float dot = 0.f;
#pragma unroll
  for (int e = 0; e < 8; ++e) {
    v[e] = *(const bf16x8*)(qp + e * 8);
#pragma unroll
    for (int i = 0; i < 8; ++i) dot += (float)v[e][i] * ks[h * 64 + e * 8 + i];
  }
  const float z = 1.0f / (dot + 1e-6f);
#pragma unroll
  for (int e = 0; e < 8; ++e) {
    bf16x8 o;
#pragma unroll
    for (int i = 0; i < 8; ++i) o[i] = (__bf16)((float)v[e][i] * z);
    *(bf16x8*)(qp + e * 8) = o;
  }
}

extern "C" void kernel_launch(void* const* d_in, const int* in_sizes, int n_in,
                              void* d_out, int out_size, void* d_ws, size_t ws_size,
                              hipStream_t stream) {
  const float* x  = (const float*)d_in[0];
  const float* wq = (const float*)d_in[1];
  const float* bq = (const float*)d_in[2];
  const float* wk = (const float*)d_in[3];
  const float* bk = (const float*)d_in[4];
  const float* wv = (const float*)d_in[5];
  const float* bv = (const float*)d_in[6];
  const float* wo = (const float*)d_in[7];
  const float* bo = (const float*)d_in[8];
  float* out = (float*)d_out;

  char* p = (char*)d_ws;
  __bf16* xt    = (__bf16*)p; p += (size_t)BATCH * LLEN * CCH * 2;  // 32MB
  __bf16* qt    = (__bf16*)p; p += (size_t)BATCH * LLEN * CCH * 2;  // 32MB
  __bf16* kcm   = (__bf16*)p; p += (size_t)BATCH * CCH * LLEN * 2;  // 32MB
  __bf16* vcm   = (__bf16*)p; p += (size_t)BATCH * CCH * LLEN * 2;  // 32MB
  __bf16* wqkvb = (__bf16*)p; p += (size_t)M1 * CCH * 2;
  float*  biasq = (float*)p;  p += (size_t)M1 * 4;
  float*  ksumf = (float*)p;  p += (size_t)BATCH * CCH * 4;
  float*  part  = (float*)p;  p += (size_t)8 * 64 * HD * HD * 4;    // 8MB
  float*  pks   = (float*)p;  p += (size_t)8 * 64 * 64 * 4;         // 128KB
  __bf16* wokv  = (__bf16*)p; p += (size_t)BATCH * CCH * CCH * 2;   // 4MB

  pack_w<<<1024, 256, 0, stream>>>(wq, wk, wv, bq, bk, bv, wqkvb, biasq);
  transpose_x<<<dim3(64, 8, BATCH), 256, 0, stream>>>(x, xt);
  gemm128<0><<<dim3(32, 12, BATCH), 256, 0, stream>>>(wqkvb, xt, biasq, qt, kcm, vcm, nullptr);
  kv_part_k<<<dim3(8, 64), 256, 0, stream>>>(kcm, vcm, part, pks);
  kvfold_k<<<dim3(8, BATCH), 256, 0, stream>>>(part, pks, wo, wokv, ksumf);
  zscale_k<<<dim3(128, BATCH), 256, 0, stream>>>(qt, ksumf);
  gemm128<1><<<dim3(32, 4, BATCH), 256, 0, stream>>>(wokv, qt, bo, nullptr, nullptr,
                                                     nullptr, out);
}